// Round 6
// baseline (210.088 us; speedup 1.0000x reference)
//
#include <hip/hip_runtime.h>
#include <math.h>

#define BB 16
#define CC 256
#define HH 128
#define WW 128
#define HWSZ (HH * WW)   // 16384

typedef float floatx4 __attribute__((ext_vector_type(4)));

// ===========================================================================
// PRIMARY PATH (needs 35 MB workspace)
// ===========================================================================

// ---------------------------------------------------------------------------
// K1: partial channel pool. Block = (batch, 16-channel group, half plane).
// Footprint per block = 512 KB CONTIGUOUS; access = 16 streams advancing in
// 4 KB steps (256 thr x 16 B). Per-pixel partial sum/max over 16 channels.
// Caching loads ON PURPOSE: x must stay L3-resident for K3's re-read.
// ---------------------------------------------------------------------------
__global__ __launch_bounds__(256) void pool_partial_kernel(const float* __restrict__ x,
                                                           float* __restrict__ psum,
                                                           float* __restrict__ pmax) {
    const int blk  = blockIdx.x;          // 0..511
    const int b    = blk >> 5;
    const int r    = blk & 31;
    const int cg   = r >> 1;              // 0..15 channel group
    const int half = r & 1;               // half plane

    const float* xb = x + (size_t)(b * CC + cg * 16) * HWSZ + half * (HWSZ / 2);
    float* ps = psum + (size_t)(b * 16 + cg) * HWSZ + half * (HWSZ / 2);
    float* pm = pmax + (size_t)(b * 16 + cg) * HWSZ + half * (HWSZ / 2);

    for (int k = 0; k < 8; ++k) {
        const int g4 = (k * 256 + threadIdx.x) * 4;   // float offset in half-plane
        const float* p0 = xb + g4;

        float4 s = make_float4(0.f, 0.f, 0.f, 0.f);
        float4 m = make_float4(-INFINITY, -INFINITY, -INFINITY, -INFINITY);
        #pragma unroll
        for (int c = 0; c < 16; ++c) {
            float4 v = *(const float4*)(p0 + (size_t)c * HWSZ);
            s.x += v.x; s.y += v.y; s.z += v.z; s.w += v.w;
            m.x = fmaxf(m.x, v.x); m.y = fmaxf(m.y, v.y);
            m.z = fmaxf(m.z, v.z); m.w = fmaxf(m.w, v.w);
        }
        *(float4*)(ps + g4) = s;
        *(float4*)(pm + g4) = m;
    }
}

// ---------------------------------------------------------------------------
// K2a: final reduce of the 16 partials per pixel -> avg/max planes.
// 32 MB in (cache-hot), 2 MB out. One f4-group per thread.
// ---------------------------------------------------------------------------
__global__ __launch_bounds__(256) void pool_final_kernel(const float* __restrict__ psum,
                                                         const float* __restrict__ pmax,
                                                         float* __restrict__ avg_out,
                                                         float* __restrict__ max_out) {
    const int i = blockIdx.x * 256 + threadIdx.x;  // 0..65535 f4-groups
    const int b = i >> 12;
    const int g4 = (i & 4095) * 4;

    const float* ps = psum + (size_t)b * 16 * HWSZ + g4;
    const float* pm = pmax + (size_t)b * 16 * HWSZ + g4;

    float4 s = make_float4(0.f, 0.f, 0.f, 0.f);
    float4 m = make_float4(-INFINITY, -INFINITY, -INFINITY, -INFINITY);
    #pragma unroll
    for (int cg = 0; cg < 16; ++cg) {
        float4 v = *(const float4*)(ps + (size_t)cg * HWSZ);
        s.x += v.x; s.y += v.y; s.z += v.z; s.w += v.w;
        float4 u = *(const float4*)(pm + (size_t)cg * HWSZ);
        m.x = fmaxf(m.x, u.x); m.y = fmaxf(m.y, u.y);
        m.z = fmaxf(m.z, u.z); m.w = fmaxf(m.w, u.w);
    }
    const float inv = 1.0f / CC;
    s.x *= inv; s.y *= inv; s.z *= inv; s.w *= inv;
    *(float4*)(avg_out + (size_t)b * HWSZ + g4) = s;
    *(float4*)(max_out + (size_t)b * HWSZ + g4) = m;
}

// ---------------------------------------------------------------------------
// K2b: 7x7 conv over [avg;max] + sigmoid -> M (16x128x128). Cache-hot.
// ---------------------------------------------------------------------------
__global__ __launch_bounds__(256) void conv_kernel(const float* __restrict__ avg_in,
                                                   const float* __restrict__ max_in,
                                                   const float* __restrict__ wgt,
                                                   float* __restrict__ Mout) {
    __shared__ float sw[98];
    if (threadIdx.x < 98) sw[threadIdx.x] = wgt[threadIdx.x];
    __syncthreads();

    const int idx = blockIdx.x * blockDim.x + threadIdx.x;  // 0 .. 262143
    const int b  = idx >> 14;
    const int hw = idx & (HWSZ - 1);
    const int h  = hw >> 7;
    const int w  = hw & 127;

    const float* ap = avg_in + (size_t)b * HWSZ;
    const float* mp = max_in + (size_t)b * HWSZ;

    float acc = 0.f;
    #pragma unroll
    for (int kh = 0; kh < 7; ++kh) {
        const int hh = h + kh - 3;
        if (hh < 0 || hh >= HH) continue;
        #pragma unroll
        for (int kw = 0; kw < 7; ++kw) {
            const int ww2 = w + kw - 3;
            if (ww2 < 0 || ww2 >= WW) continue;
            const int off = hh * WW + ww2;
            acc += ap[off] * sw[kh * 7 + kw];
            acc += mp[off] * sw[49 + kh * 7 + kw];
        }
    }
    Mout[idx] = 1.0f / (1.0f + expf(-acc));
}

// ---------------------------------------------------------------------------
// K3: out = x * M. Fully SEQUENTIAL i-major traversal, backwards (x tail is
// most-recently-cached in L3 from K1's forward stream). NT loads (last use
// of x) + NT stores (out must not evict x). M loads cached (1 MB, hot).
// ---------------------------------------------------------------------------
__global__ __launch_bounds__(256) void mul_kernel(const float* __restrict__ x,
                                                  const float* __restrict__ Mv,
                                                  float* __restrict__ out) {
    const int n4     = BB * CC * HWSZ / 4;          // 16,777,216
    const int stride = gridDim.x * blockDim.x;      // 1,048,576
    const int rbid   = gridDim.x - 1 - blockIdx.x;
    const int base   = rbid * blockDim.x + threadIdx.x;
    const int nIter  = n4 / stride;                 // 16

    const floatx4* xv4 = (const floatx4*)x;
    floatx4*       ov4 = (floatx4*)out;

    for (int it = nIter - 1; it >= 0; --it) {
        const int i   = it * stride + base;
        const int b   = i >> 20;
        const int hw4 = i & 4095;
        floatx4 xv = __builtin_nontemporal_load(xv4 + i);
        floatx4 mv = *(const floatx4*)(Mv + ((size_t)b << 14) + (hw4 << 2));
        __builtin_nontemporal_store(xv * mv, ov4 + i);
    }
}

// ===========================================================================
// FALLBACK PATH (R5 kernels, needs only 2 MB workspace)
// ===========================================================================
__global__ __launch_bounds__(256) void pool_kernel(const float* __restrict__ x,
                                                   float* __restrict__ avg_out,
                                                   float* __restrict__ max_out) {
    const int tf4   = threadIdx.x & 63;
    const int split = threadIdx.x >> 6;
    const int p0    = blockIdx.x * 256;
    const int b     = p0 >> 14;
    const int hw    = (p0 & (HWSZ - 1)) + tf4 * 4;

    const float* xb = x + (size_t)b * CC * HWSZ + hw;

    float4 s = make_float4(0.f, 0.f, 0.f, 0.f);
    float4 m = make_float4(-INFINITY, -INFINITY, -INFINITY, -INFINITY);

    const int c0 = split * 64;
    #pragma unroll 8
    for (int i = 0; i < 64; ++i) {
        float4 v = *(const float4*)(xb + (size_t)(c0 + i) * HWSZ);
        s.x += v.x; s.y += v.y; s.z += v.z; s.w += v.w;
        m.x = fmaxf(m.x, v.x); m.y = fmaxf(m.y, v.y);
        m.z = fmaxf(m.z, v.z); m.w = fmaxf(m.w, v.w);
    }

    __shared__ float4 sS[4][64];
    __shared__ float4 sM[4][64];
    sS[split][tf4] = s;
    sM[split][tf4] = m;
    __syncthreads();

    for (int off = 2; off >= 1; off >>= 1) {
        if (split < off) {
            float4 a  = sS[split][tf4], b2 = sS[split + off][tf4];
            a.x += b2.x; a.y += b2.y; a.z += b2.z; a.w += b2.w;
            sS[split][tf4] = a;
            float4 ma = sM[split][tf4], mb = sM[split + off][tf4];
            ma.x = fmaxf(ma.x, mb.x); ma.y = fmaxf(ma.y, mb.y);
            ma.z = fmaxf(ma.z, mb.z); ma.w = fmaxf(ma.w, mb.w);
            sM[split][tf4] = ma;
        }
        __syncthreads();
    }

    if (split == 0) {
        float4 a = sS[0][tf4];
        const float inv = 1.0f / CC;
        a.x *= inv; a.y *= inv; a.z *= inv; a.w *= inv;
        *(float4*)(avg_out + (size_t)b * HWSZ + hw) = a;
        *(float4*)(max_out + (size_t)b * HWSZ + hw) = sM[0][tf4];
    }
}

__global__ __launch_bounds__(256) void convmul_kernel(const float* __restrict__ x,
                                                      const float* __restrict__ avg_p,
                                                      const float* __restrict__ max_p,
                                                      const float* __restrict__ wgt,
                                                      float* __restrict__ out) {
    __shared__ float sw[98];
    __shared__ float sMl[256];

    const int tid = threadIdx.x;
    if (tid < 98) sw[tid] = wgt[tid];
    __syncthreads();

    const int strip = blockIdx.x;
    const int b     = strip >> 6;
    const int h0    = (strip & 63) * 2;

    {
        const int hl = tid >> 7;
        const int w  = tid & 127;
        const int h  = h0 + hl;
        const float* ap = avg_p + (size_t)b * HWSZ;
        const float* mp = max_p + (size_t)b * HWSZ;

        float acc = 0.f;
        #pragma unroll
        for (int kh = 0; kh < 7; ++kh) {
            const int hh = h + kh - 3;
            if (hh < 0 || hh >= HH) continue;
            #pragma unroll
            for (int kw = 0; kw < 7; ++kw) {
                const int ww2 = w + kw - 3;
                if (ww2 < 0 || ww2 >= WW) continue;
                const int off = hh * WW + ww2;
                acc += ap[off] * sw[kh * 7 + kw];
                acc += mp[off] * sw[49 + kh * 7 + kw];
            }
        }
        sMl[tid] = 1.0f / (1.0f + expf(-acc));
    }
    __syncthreads();

    const int g    = tid & 63;
    const int csub = tid >> 6;
    const floatx4 mv = ((const floatx4*)sMl)[g];

    const size_t base = (size_t)b * CC * HWSZ + (size_t)h0 * WW + (size_t)g * 4;
    const float* xp = x + base;
    float*       op = out + base;

    #pragma unroll 4
    for (int c = 0; c < 64; ++c) {
        const size_t coff = (size_t)(c * 4 + csub) * HWSZ;
        floatx4 xv = __builtin_nontemporal_load((const floatx4*)(xp + coff));
        __builtin_nontemporal_store(xv * mv, (floatx4*)(op + coff));
    }
}

extern "C" void kernel_launch(void* const* d_in, const int* in_sizes, int n_in,
                              void* d_out, int out_size, void* d_ws, size_t ws_size,
                              hipStream_t stream) {
    const float* x   = (const float*)d_in[0];
    const float* wgt = (const float*)d_in[1];
    float* out = (float*)d_out;

    const size_t planeB = (size_t)BB * HWSZ;            // 262144 floats / plane set
    const size_t need = (2 * 16 * planeB + 2 * planeB + planeB) * sizeof(float); // 35 MB

    if (ws_size >= need) {
        float* psum  = (float*)d_ws;                    // 16 MB
        float* pmax  = psum + 16 * planeB;              // 16 MB
        float* avg_p = pmax + 16 * planeB;              // 1 MB
        float* max_p = avg_p + planeB;                  // 1 MB
        float* Mbuf  = max_p + planeB;                  // 1 MB

        pool_partial_kernel<<<512, 256, 0, stream>>>(x, psum, pmax);
        pool_final_kernel<<<256, 256, 0, stream>>>(psum, pmax, avg_p, max_p);
        conv_kernel<<<(BB * HWSZ) / 256, 256, 0, stream>>>(avg_p, max_p, wgt, Mbuf);
        mul_kernel<<<4096, 256, 0, stream>>>(x, Mbuf, out);
    } else {
        float* avg_p = (float*)d_ws;
        float* max_p = avg_p + planeB;
        pool_kernel<<<1024, 256, 0, stream>>>(x, avg_p, max_p);
        convmul_kernel<<<1024, 256, 0, stream>>>(x, avg_p, max_p, wgt, out);
    }
}

// Round 7
// 165.233 us; speedup vs baseline: 1.2715x; 1.2715x over previous
//
#include <hip/hip_runtime.h>
#include <math.h>

#define BB 16
#define CC 256
#define HH 128
#define WW 128
#define HWSZ (HH * WW)   // 16384

typedef float floatx4 __attribute__((ext_vector_type(4)));

// ---------------------------------------------------------------------------
// Kernel 1: channel-wise avg & max pool.
// Tile = 256 pixels. Block = 256 threads = 64 f4-lanes x 4 channel-splits.
// Every wave load covers 1 KB contiguous. Each thread reduces 64 channels.
// A/B CHANGE vs R5: x loads are NONTEMPORAL — do NOT allocate x into L2/L3.
// Theory: L3 allocation churn (256 MB through a 256 MB LLC) throttles the
// read stream more than the later L3 hits save.
// ---------------------------------------------------------------------------
__global__ __launch_bounds__(256) void pool_kernel(const float* __restrict__ x,
                                                   float* __restrict__ avg_out,
                                                   float* __restrict__ max_out) {
    const int tf4   = threadIdx.x & 63;   // f4 group within 256-px tile
    const int split = threadIdx.x >> 6;   // 0..3 channel split
    const int p0    = blockIdx.x * 256;   // first pixel of tile
    const int b     = p0 >> 14;           // tiles never straddle batch
    const int hw    = (p0 & (HWSZ - 1)) + tf4 * 4;

    const floatx4* xb = (const floatx4*)(x + (size_t)b * CC * HWSZ + hw);

    floatx4 s = (floatx4)(0.f);
    floatx4 m = (floatx4)(-INFINITY);

    const int c0 = split * 64;
    #pragma unroll 8
    for (int i = 0; i < 64; ++i) {
        floatx4 v = __builtin_nontemporal_load(xb + (size_t)(c0 + i) * (HWSZ / 4));
        s += v;
        m.x = fmaxf(m.x, v.x); m.y = fmaxf(m.y, v.y);
        m.z = fmaxf(m.z, v.z); m.w = fmaxf(m.w, v.w);
    }

    __shared__ floatx4 sS[4][64];
    __shared__ floatx4 sM[4][64];
    sS[split][tf4] = s;
    sM[split][tf4] = m;
    __syncthreads();

    for (int off = 2; off >= 1; off >>= 1) {
        if (split < off) {
            floatx4 a  = sS[split][tf4] + sS[split + off][tf4];
            sS[split][tf4] = a;
            floatx4 ma = sM[split][tf4], mb = sM[split + off][tf4];
            ma.x = fmaxf(ma.x, mb.x); ma.y = fmaxf(ma.y, mb.y);
            ma.z = fmaxf(ma.z, mb.z); ma.w = fmaxf(ma.w, mb.w);
            sM[split][tf4] = ma;
        }
        __syncthreads();
    }

    if (split == 0) {
        floatx4 a = sS[0][tf4] * (1.0f / CC);
        *(floatx4*)(avg_out + (size_t)b * HWSZ + hw) = a;
        *(floatx4*)(max_out + (size_t)b * HWSZ + hw) = sM[0][tf4];
    }
}

// ---------------------------------------------------------------------------
// Kernel 2: conv(7x7)+sigmoid fused with the broadcast multiply (R5 kernel,
// unchanged). x reads are NT (now expected to stream from HBM), out stores NT.
// ---------------------------------------------------------------------------
__global__ __launch_bounds__(256) void convmul_kernel(const float* __restrict__ x,
                                                      const float* __restrict__ avg_p,
                                                      const float* __restrict__ max_p,
                                                      const float* __restrict__ wgt,
                                                      float* __restrict__ out) {
    __shared__ float sw[98];
    __shared__ float sMl[256];

    const int tid = threadIdx.x;
    if (tid < 98) sw[tid] = wgt[tid];
    __syncthreads();

    const int strip = blockIdx.x;        // 0..1023
    const int b     = strip >> 6;        // 64 strips per batch
    const int h0    = (strip & 63) * 2;  // strip's first row

    // ---- phase a: conv + sigmoid for this strip's 256 pixels ----
    {
        const int hl = tid >> 7;
        const int w  = tid & 127;
        const int h  = h0 + hl;
        const float* ap = avg_p + (size_t)b * HWSZ;
        const float* mp = max_p + (size_t)b * HWSZ;

        float acc = 0.f;
        #pragma unroll
        for (int kh = 0; kh < 7; ++kh) {
            const int hh = h + kh - 3;
            if (hh < 0 || hh >= HH) continue;
            #pragma unroll
            for (int kw = 0; kw < 7; ++kw) {
                const int ww2 = w + kw - 3;
                if (ww2 < 0 || ww2 >= WW) continue;
                const int off = hh * WW + ww2;
                acc += ap[off] * sw[kh * 7 + kw];
                acc += mp[off] * sw[49 + kh * 7 + kw];
            }
        }
        sMl[tid] = 1.0f / (1.0f + expf(-acc));
    }
    __syncthreads();

    // ---- phase b: out = x * M over all 256 channels ----
    const int g    = tid & 63;
    const int csub = tid >> 6;
    const floatx4 mv = ((const floatx4*)sMl)[g];

    const size_t base = (size_t)b * CC * HWSZ + (size_t)h0 * WW + (size_t)g * 4;
    const float* xp = x + base;
    float*       op = out + base;

    #pragma unroll 4
    for (int c = 0; c < 64; ++c) {
        const size_t coff = (size_t)(c * 4 + csub) * HWSZ;
        floatx4 xv = __builtin_nontemporal_load((const floatx4*)(xp + coff));
        __builtin_nontemporal_store(xv * mv, (floatx4*)(op + coff));
    }
}

extern "C" void kernel_launch(void* const* d_in, const int* in_sizes, int n_in,
                              void* d_out, int out_size, void* d_ws, size_t ws_size,
                              hipStream_t stream) {
    const float* x   = (const float*)d_in[0];
    const float* wgt = (const float*)d_in[1];
    float* out = (float*)d_out;

    float* avg_p = (float*)d_ws;                   // 1 MB
    float* max_p = avg_p + (size_t)BB * HWSZ;      // 1 MB

    pool_kernel<<<1024, 256, 0, stream>>>(x, avg_p, max_p);
    convmul_kernel<<<1024, 256, 0, stream>>>(x, avg_p, max_p, wgt, out);
}